// Round 21
// baseline (256.402 us; speedup 1.0000x reference)
//
#include <hip/hip_runtime.h>
#include <math.h>

#define Bn 2
#define DM 192
#define DI 384
#define DS 16
#define HH 64
#define WW 64
#define HW 4096
#define ND 4

typedef __attribute__((ext_vector_type(2))) float v2f;
union Q4 { float4 f4; v2f v2[2]; };

__device__ __forceinline__ float fastrcp(float x) { return __builtin_amdgcn_rcpf(x); }
__device__ __forceinline__ float fsig(float x) {
    return fastrcp(1.0f + __expf(-x));
}

// Lane shifts in the VALU pipe. row_shr/shl within 16-lane rows; boundary
// lanes patched with readlane + v_writelane_b32. Full-exec straight-line
// only (DPP reads of exec=0 lanes return bound_ctrl 0 — r13/r15 bug).
#define WLANE(r, s, L) asm("v_writelane_b32 %0, %1, " #L : "+v"(r) : "s"(s))

__device__ __forceinline__ float shift_up(float x) {
    int xi = __float_as_int(x);
    int r = __builtin_amdgcn_mov_dpp(xi, 0x111, 0xF, 0xF, true);  // row_shr:1
    int t15 = __builtin_amdgcn_readlane(xi, 15);
    int t31 = __builtin_amdgcn_readlane(xi, 31);
    int t47 = __builtin_amdgcn_readlane(xi, 47);
    WLANE(r, t15, 16);
    WLANE(r, t31, 32);
    WLANE(r, t47, 48);
    return __int_as_float(r);
}
__device__ __forceinline__ float shift_dn(float x) {
    int xi = __float_as_int(x);
    int r = __builtin_amdgcn_mov_dpp(xi, 0x101, 0xF, 0xF, true);  // row_shl:1
    int t16 = __builtin_amdgcn_readlane(xi, 16);
    int t32 = __builtin_amdgcn_readlane(xi, 32);
    int t48 = __builtin_amdgcn_readlane(xi, 48);
    WLANE(r, t16, 15);
    WLANE(r, t32, 31);
    WLANE(r, t48, 47);
    return __int_as_float(r);
}

// ---------------- K1: in_proj (1x1) + SiLU ----------------
// grid (16, 12, 2), block 256. Thread: 32 output channels for one pixel
// (12 groups instead of 24: halves x re-reads through L2/L3).
__global__ __launch_bounds__(256, 3) void k_inproj(const float* __restrict__ x,
                                                   const float* __restrict__ w,
                                                   float* __restrict__ hpre) {
    int og = blockIdx.y, b = blockIdx.z;
    int p = blockIdx.x * 256 + threadIdx.x;
    const float* wr = w + (size_t)og * 32 * DM;
    const float* xb = x + (size_t)b * DM * HW + p;
    float acc[32];
#pragma unroll
    for (int j = 0; j < 32; ++j) acc[j] = 0.f;
    for (int c = 0; c < DM; c += 4) {
        float x0 = xb[(size_t)(c + 0) * HW];
        float x1 = xb[(size_t)(c + 1) * HW];
        float x2 = xb[(size_t)(c + 2) * HW];
        float x3 = xb[(size_t)(c + 3) * HW];
#pragma unroll
        for (int j = 0; j < 32; ++j) {
            const float* wj = wr + j * DM + c;  // wave-uniform -> SGPR
            acc[j] = fmaf(wj[0], x0, fmaf(wj[1], x1, fmaf(wj[2], x2, fmaf(wj[3], x3, acc[j]))));
        }
    }
    float* hb = hpre + (size_t)b * DI * HW + (size_t)(og * 32) * HW + p;
#pragma unroll
    for (int j = 0; j < 32; ++j) {
        float v = acc[j];
        hb[(size_t)j * HW] = v * fastrcp(1.0f + __expf(-v));
    }
}

// ---------------- K2: depthwise 3x3 conv + bias ----------------
// grid (16, 384, 2), block 256.
__global__ __launch_bounds__(256) void k_dwconv(const float* __restrict__ hpre,
                                                const float* __restrict__ w,
                                                const float* __restrict__ bias,
                                                float* __restrict__ h) {
    int c = blockIdx.y, b = blockIdx.z;
    int p = blockIdx.x * 256 + threadIdx.x;
    int i = p >> 6, j = p & 63;
    const float* wp = w + c * 9;
    const float* src = hpre + ((size_t)b * DI + c) * HW;
    float acc = bias[c];
#pragma unroll
    for (int di = -1; di <= 1; ++di) {
        int ii = i + di;
        if (ii < 0 || ii >= HH) continue;
#pragma unroll
        for (int dj = -1; dj <= 1; ++dj) {
            int jj = j + dj;
            if (jj < 0 || jj >= WW) continue;
            acc = fmaf(wp[(di + 1) * 3 + (dj + 1)], src[ii * WW + jj], acc);
        }
    }
    h[((size_t)b * DI + c) * HW + p] = acc;
}

// ---------------- K3: x_down -> xp column-major [b][w][q][h] ----------------
// grid (128), block 256 = 4 waves. Wave = 96-channel slice; 64 pixels/block.
__global__ __launch_bounds__(256) void k_xdown(const float* __restrict__ h,
                                               const float* __restrict__ w,
                                               float* __restrict__ xpt) {
    __shared__ float red[4][64][17];
    int tid = threadIdx.x;
    int px = tid & 63, cw = tid >> 6;
    int gp = blockIdx.x * 64 + px;
    int b = gp >> 12, p = gp & 4095;
    const float* hb = h + (size_t)b * DI * HW + p;
    int c0 = cw * 96;
    float a[16];
#pragma unroll
    for (int s = 0; s < 16; ++s) a[s] = 0.f;
    for (int cc = 0; cc < 96; cc += 4) {
        float h0 = hb[(size_t)(c0 + cc + 0) * HW];
        float h1 = hb[(size_t)(c0 + cc + 1) * HW];
        float h2 = hb[(size_t)(c0 + cc + 2) * HW];
        float h3 = hb[(size_t)(c0 + cc + 3) * HW];
#pragma unroll
        for (int s = 0; s < 16; ++s) {
            const float* ws = w + (size_t)s * DI + c0 + cc;  // wave-uniform -> s_load
            a[s] = fmaf(ws[0], h0, fmaf(ws[1], h1, fmaf(ws[2], h2, fmaf(ws[3], h3, a[s]))));
        }
    }
#pragma unroll
    for (int s = 0; s < 16; ++s) red[cw][px][s] = a[s];
    __syncthreads();
    int sg = tid >> 6;  // state quad
    float4 r;
    float* o = &r.x;
#pragma unroll
    for (int j = 0; j < 4; ++j) {
        int s = sg * 4 + j;
        o[j] = red[0][px][s] + red[1][px][s] + red[2][px][s] + red[3][px][s];
    }
    int hp = p >> 6, wp_ = p & 63;
    reinterpret_cast<float4*>(xpt)[(size_t)b * (HW * 4) + (wp_ * 4 + sg) * 64 + hp] = r;
}

// Packed 16-dot: 8 v_pk_fma_f32 in two chains + horizontal add.
__device__ __forceinline__ float dot16p(const v2f* __restrict__ W,
                                        const Q4& a0, const Q4& a1,
                                        const Q4& a2, const Q4& a3) {
    v2f t0 = W[0] * a0.v2[0];
    v2f t1 = W[1] * a0.v2[1];
    t0 = __builtin_elementwise_fma(W[2], a1.v2[0], t0);
    t1 = __builtin_elementwise_fma(W[3], a1.v2[1], t1);
    t0 = __builtin_elementwise_fma(W[4], a2.v2[0], t0);
    t1 = __builtin_elementwise_fma(W[5], a2.v2[1], t1);
    t0 = __builtin_elementwise_fma(W[6], a3.v2[0], t0);
    t1 = __builtin_elementwise_fma(W[7], a3.v2[1], t1);
    v2f t = t0 + t1;
    return t.x + t.y;
}

// ---------------- K4: fused gate-recurrent scan, all 4 directions ----------------
// grid (384, 2), block 256 (4 waves = 4 directions, lane = h). r17 build.
__global__ __launch_bounds__(256, 3) void k_scan(const float* __restrict__ h,
                                                 const float* __restrict__ xpt,
                                                 const float* __restrict__ wup,
                                                 const float* __restrict__ lup,
                                                 const float* __restrict__ uup,
                                                 const float* __restrict__ dup,
                                                 const float* __restrict__ mw,
                                                 float* __restrict__ y) {
    int c = blockIdx.x, b = blockIdx.y;
    int tid = threadIdx.x;
    int d = tid >> 6, hl = tid & 63;

    __shared__ float htile[64][65];
    __shared__ float acc[64][65];

    const float* hb = h + ((size_t)b * DI + c) * HW;
    for (int i = tid; i < HW; i += 256) {
        htile[i >> 6][i & 63] = hb[i];
        acc[i >> 6][i & 63] = 0.f;
    }

    int row = d * DI + c;
    const float* p1 = wup + (size_t)row * DS;
    const float* p2 = wup + (size_t)(4 * DI + row) * DS;
    const float* p3 = wup + (size_t)(8 * DI + row) * DS;
    const float* pL = lup + (size_t)row * DS;
    const float* pU = uup + (size_t)row * DS;
    const float* pD = dup + (size_t)row * DS;
    float md = mw[d];
    v2f w1p[8], w2p[8], w3p[8], wLp[8], wUp[8], wDp[8];
#pragma unroll
    for (int k = 0; k < 8; ++k) {
        w1p[k] = *reinterpret_cast<const v2f*>(p1 + 2 * k);
        w2p[k] = *reinterpret_cast<const v2f*>(p2 + 2 * k);
        w3p[k] = *reinterpret_cast<const v2f*>(p3 + 2 * k);
        wLp[k] = *reinterpret_cast<const v2f*>(pL + 2 * k);
        wUp[k] = md * *reinterpret_cast<const v2f*>(pU + 2 * k);
        wDp[k] = md * *reinterpret_cast<const v2f*>(pD + 2 * k);
    }

    int xstep = (d & 1) ? 65 : 1;
    int xbase = (d & 1) ? hl : hl * 65;
    if (d & 2) { xbase += xstep * 63; xstep = -xstep; }
    const float* xptr = &htile[0][0] + xbase;

    bool isTop = (hl == 0), isBot = (hl == 63);
    float topMul = isTop ? 0.f : 1.f;
    float botMul = isBot ? 0.f : 1.f;

    float* accp = &acc[hl][0];

    const float4* xg = reinterpret_cast<const float4*>(xpt) + (size_t)b * (HW * 4) + hl;

#define LOADQ(R0, R1, R2, R3, wcol) { \
    const float4* pp_ = xg + (size_t)(wcol) * 256; \
    R0.f4 = pp_[0]; R1.f4 = pp_[64]; R2.f4 = pp_[128]; R3.f4 = pp_[192]; }

#define PREP(g1S, g2S, g3S, invS, LS, US, DvS, XS, R0, R1, R2, R3) { \
    g1S = dot16p(w1p, R0, R1, R2, R3); \
    g2S = dot16p(w2p, R0, R1, R2, R3); \
    g3S = dot16p(w3p, R0, R1, R2, R3); \
    LS  = dot16p(wLp, R0, R1, R2, R3); \
    US  = dot16p(wUp, R0, R1, R2, R3); \
    DvS = dot16p(wDp, R0, R1, R2, R3); \
    g1S = fsig(g1S); g2S = fsig(g2S); g3S = fsig(g3S); \
    float ss_ = fmaf(g1S, topMul, fmaf(g3S, botMul, g2S)); \
    invS = fastrcp(fmaxf(ss_, 1e-7f)); \
    XS = *xptr; xptr += xstep; }

#define COMB(g1S, g2S, g3S, invS, LS, US, DvS, XS) { \
    float upv_ = topMul * shift_up(hprev); \
    float dnv_ = botMul * shift_dn(hprev); \
    float hnew_ = fmaf(LS, XS, invS * fmaf(g1S, upv_, fmaf(g2S, hprev, g3S * dnv_))); \
    atomicAdd(accp, fmaf(hnew_, US, XS * DvS)); accp += 1; \
    hprev = hnew_; }

    Q4 A0, A1, A2, A3, B0, B1, B2, B3;
    float g1a, g2a, g3a, inva, La, Ua, Dva, Xa;
    float g1b, g2b, g3b, invb, Lb, Ub, Dvb, Xb;
    float hprev = 0.f;

    LOADQ(A0, A1, A2, A3, 0);
    __syncthreads();
    LOADQ(B0, B1, B2, B3, 1);

    for (int w = 0; w < 64; w += 2) {
        PREP(g1a, g2a, g3a, inva, La, Ua, Dva, Xa, A0, A1, A2, A3);
        int wn2 = (w + 2 < 64) ? w + 2 : 63;
        LOADQ(A0, A1, A2, A3, wn2);
        COMB(g1a, g2a, g3a, inva, La, Ua, Dva, Xa);
        PREP(g1b, g2b, g3b, invb, Lb, Ub, Dvb, Xb, B0, B1, B2, B3);
        int wn3 = (w + 3 < 64) ? w + 3 : 63;
        LOADQ(B0, B1, B2, B3, wn3);
        COMB(g1b, g2b, g3b, invb, Lb, Ub, Dvb, Xb);
    }
#undef LOADQ
#undef PREP
#undef COMB

    __syncthreads();
    float* yb = y + ((size_t)b * DI + c) * HW;
    for (int i = tid; i < HW; i += 256) yb[i] = acc[i >> 6][i & 63];
}

// ---------------- K5: LayerNorm2d fused with GRN sumsq ----------------
// grid (512), block 256. gxsum must be zeroed beforehand.
__global__ __launch_bounds__(256) void k_ln(float* __restrict__ y,
                                            const float* __restrict__ nw,
                                            const float* __restrict__ nb,
                                            float* __restrict__ gxsum) {
    int lpx = threadIdx.x & 15, chunk = threadIdx.x >> 4;
    int gp = blockIdx.x * 16 + lpx;  // global pixel 0..8191
    int b = gp >> 12, p = gp & 4095;
    float* yb = y + (size_t)b * DI * HW + p;

    float vv[24];
    float s = 0.f, s2 = 0.f;
#pragma unroll
    for (int ci = 0; ci < 24; ++ci) {
        float v = yb[(size_t)(chunk * 24 + ci) * HW];
        vv[ci] = v;
        s += v;
        s2 = fmaf(v, v, s2);
    }
    __shared__ float S[16][17], S2[16][17];
    __shared__ float ss[16][385];
    S[chunk][lpx] = s;
    S2[chunk][lpx] = s2;
    __syncthreads();
    float ts = 0.f, ts2 = 0.f;
#pragma unroll
    for (int k = 0; k < 16; ++k) { ts += S[k][lpx]; ts2 += S2[k][lpx]; }
    float mu = ts * (1.0f / DI);
    float var = ts2 * (1.0f / DI) - mu * mu;
    float inv = rsqrtf(var + 1e-5f);
#pragma unroll
    for (int ci = 0; ci < 24; ++ci) {
        int cch = chunk * 24 + ci;
        float v = (vv[ci] - mu) * inv;
        float o = fmaf(v, nw[cch], nb[cch]);
        yb[(size_t)cch * HW] = o;
        ss[lpx][cch] = o * o;
    }
    __syncthreads();
    for (int cc = threadIdx.x; cc < DI; cc += 256) {
        float t = 0.f;
#pragma unroll
        for (int k = 0; k < 16; ++k) t += ss[k][cc];
        atomicAdd(&gxsum[b * DI + cc], t);
    }
}

// ---------------- K8: out_proj GEMM with inline GRN scale/shift ----------------
// grid (16, 12, 2), block 256. Thread: 16 output channels for one pixel
// (12 groups instead of 24: halves y re-reads through L2/L3). Prologue
// recomputes sc[384] into LDS from gxsum.
__global__ __launch_bounds__(256, 3) void k_outproj(const float* __restrict__ y,
                                                    const float* __restrict__ w,
                                                    const float* __restrict__ gxsum,
                                                    const float* __restrict__ gamma,
                                                    const float* __restrict__ beta,
                                                    float* __restrict__ out) {
    int og = blockIdx.y, b = blockIdx.z;
    int tid = threadIdx.x;
    __shared__ float scl[DI];
    __shared__ float red[4];
    __shared__ float meanv;
    {
        const float* g = gxsum + b * DI;
        float g0 = sqrtf(g[tid]);
        float g1 = (tid < DI - 256) ? sqrtf(g[tid + 256]) : 0.f;
        float sgx = g0 + g1;
#pragma unroll
        for (int o = 32; o > 0; o >>= 1) sgx += __shfl_down(sgx, o);
        if ((tid & 63) == 0) red[tid >> 6] = sgx;
        __syncthreads();
        if (tid == 0) meanv = (red[0] + red[1] + red[2] + red[3]) * (1.0f / DI);
        __syncthreads();
        float m = meanv + 1e-6f;
        scl[tid] = 1.0f + gamma[tid] * (g0 / m);
        if (tid < DI - 256) scl[tid + 256] = 1.0f + gamma[tid + 256] * (g1 / m);
        __syncthreads();
    }
    int p = blockIdx.x * 256 + tid;
    const float* wr = w + (size_t)og * 16 * DI;
    const float* yb = y + (size_t)b * DI * HW + p;
    float acc[16];
#pragma unroll
    for (int j = 0; j < 16; ++j) acc[j] = 0.f;
    for (int c = 0; c < DI; c += 4) {
        float v0 = fmaf(yb[(size_t)(c + 0) * HW], scl[c + 0], beta[c + 0]);
        float v1 = fmaf(yb[(size_t)(c + 1) * HW], scl[c + 1], beta[c + 1]);
        float v2 = fmaf(yb[(size_t)(c + 2) * HW], scl[c + 2], beta[c + 2]);
        float v3 = fmaf(yb[(size_t)(c + 3) * HW], scl[c + 3], beta[c + 3]);
#pragma unroll
        for (int j = 0; j < 16; ++j) {
            const float* wj = wr + j * DI + c;  // wave-uniform -> SGPR
            acc[j] = fmaf(wj[0], v0, fmaf(wj[1], v1, fmaf(wj[2], v2, fmaf(wj[3], v3, acc[j]))));
        }
    }
    float* ob = out + (size_t)b * DM * HW + (size_t)(og * 16) * HW + p;
#pragma unroll
    for (int j = 0; j < 16; ++j) ob[(size_t)j * HW] = acc[j];
}

extern "C" void kernel_launch(void* const* d_in, const int* in_sizes, int n_in,
                              void* d_out, int out_size, void* d_ws, size_t ws_size,
                              hipStream_t stream) {
    (void)in_sizes; (void)n_in; (void)out_size; (void)ws_size;
    const float* x          = (const float*)d_in[0];
    const float* in_proj_w  = (const float*)d_in[1];
    const float* dwconv_w   = (const float*)d_in[2];
    const float* dwconv_b   = (const float*)d_in[3];
    const float* x_down_w   = (const float*)d_in[4];
    const float* w_up_w     = (const float*)d_in[5];
    const float* l_up_w     = (const float*)d_in[6];
    const float* u_up_w     = (const float*)d_in[7];
    const float* d_up_w     = (const float*)d_in[8];
    const float* m_w        = (const float*)d_in[9];
    const float* grn_gamma  = (const float*)d_in[10];
    const float* grn_beta   = (const float*)d_in[11];
    const float* norm_w     = (const float*)d_in[12];
    const float* norm_b     = (const float*)d_in[13];
    const float* out_proj_w = (const float*)d_in[14];

    float* ws = (float*)d_ws;
    const size_t NBIG = (size_t)Bn * DI * HW;
    float* hpre = ws;                  // [B,DI,H,W], later reused as y
    float* hbuf = ws + NBIG;           // [B,DI,H,W] post-dwconv
    float* xpt  = ws + 2 * NBIG;       // [B,W,4,64] column-major xp
    float* gx   = ws + 2 * NBIG + (size_t)Bn * HW * DS;
    float* y    = hpre;

    k_inproj<<<dim3(16, 12, 2), 256, 0, stream>>>(x, in_proj_w, hpre);
    k_dwconv<<<dim3(16, DI, Bn), 256, 0, stream>>>(hpre, dwconv_w, dwconv_b, hbuf);
    k_xdown<<<dim3(128), 256, 0, stream>>>(hbuf, x_down_w, xpt);
    k_scan<<<dim3(DI, Bn), 256, 0, stream>>>(hbuf, xpt, w_up_w, l_up_w, u_up_w,
                                             d_up_w, m_w, y);
    hipMemsetAsync(gx, 0, Bn * DI * sizeof(float), stream);
    k_ln<<<dim3(512), 256, 0, stream>>>(y, norm_w, norm_b, gx);
    k_outproj<<<dim3(16, 12, 2), 256, 0, stream>>>(y, out_proj_w, gx, grn_gamma,
                                                   grn_beta, (float*)d_out);
}

// Round 22
// 201.634 us; speedup vs baseline: 1.2716x; 1.2716x over previous
//
#include <hip/hip_runtime.h>
#include <math.h>

#define Bn 2
#define DM 192
#define DI 384
#define DS 16
#define HH 64
#define WW 64
#define HW 4096
#define ND 4

typedef __attribute__((ext_vector_type(2))) float v2f;
union Q4 { float4 f4; v2f v2[2]; };

__device__ __forceinline__ float fastrcp(float x) { return __builtin_amdgcn_rcpf(x); }
__device__ __forceinline__ float fsig(float x) {
    return fastrcp(1.0f + __expf(-x));
}

// Lane shifts in the VALU pipe. row_shr/shl within 16-lane rows; boundary
// lanes patched with readlane + v_writelane_b32. Full-exec straight-line
// only (DPP reads of exec=0 lanes return bound_ctrl 0 — r13/r15 bug).
#define WLANE(r, s, L) asm("v_writelane_b32 %0, %1, " #L : "+v"(r) : "s"(s))

__device__ __forceinline__ float shift_up(float x) {
    int xi = __float_as_int(x);
    int r = __builtin_amdgcn_mov_dpp(xi, 0x111, 0xF, 0xF, true);  // row_shr:1
    int t15 = __builtin_amdgcn_readlane(xi, 15);
    int t31 = __builtin_amdgcn_readlane(xi, 31);
    int t47 = __builtin_amdgcn_readlane(xi, 47);
    WLANE(r, t15, 16);
    WLANE(r, t31, 32);
    WLANE(r, t47, 48);
    return __int_as_float(r);
}
__device__ __forceinline__ float shift_dn(float x) {
    int xi = __float_as_int(x);
    int r = __builtin_amdgcn_mov_dpp(xi, 0x101, 0xF, 0xF, true);  // row_shl:1
    int t16 = __builtin_amdgcn_readlane(xi, 16);
    int t32 = __builtin_amdgcn_readlane(xi, 32);
    int t48 = __builtin_amdgcn_readlane(xi, 48);
    WLANE(r, t16, 15);
    WLANE(r, t32, 31);
    WLANE(r, t48, 47);
    return __int_as_float(r);
}

// ---------------- K1: in_proj (1x1) + SiLU ----------------
// grid (16, 24, 2), block 256.
__global__ __launch_bounds__(256, 3) void k_inproj(const float* __restrict__ x,
                                                   const float* __restrict__ w,
                                                   float* __restrict__ hpre) {
    int og = blockIdx.y, b = blockIdx.z;
    int p = blockIdx.x * 256 + threadIdx.x;
    const float* wr = w + (size_t)og * 16 * DM;
    const float* xb = x + (size_t)b * DM * HW + p;
    float acc[16];
#pragma unroll
    for (int j = 0; j < 16; ++j) acc[j] = 0.f;
    for (int c = 0; c < DM; c += 4) {
        float x0 = xb[(size_t)(c + 0) * HW];
        float x1 = xb[(size_t)(c + 1) * HW];
        float x2 = xb[(size_t)(c + 2) * HW];
        float x3 = xb[(size_t)(c + 3) * HW];
#pragma unroll
        for (int j = 0; j < 16; ++j) {
            const float* wj = wr + j * DM + c;  // wave-uniform -> SGPR
            acc[j] = fmaf(wj[0], x0, fmaf(wj[1], x1, fmaf(wj[2], x2, fmaf(wj[3], x3, acc[j]))));
        }
    }
    float* hb = hpre + (size_t)b * DI * HW + (size_t)(og * 16) * HW + p;
#pragma unroll
    for (int j = 0; j < 16; ++j) {
        float v = acc[j];
        hb[(size_t)j * HW] = v * fastrcp(1.0f + __expf(-v));
    }
}

// ---------------- K2: depthwise 3x3 conv + bias ----------------
// grid (16, 384, 2), block 256.
__global__ __launch_bounds__(256) void k_dwconv(const float* __restrict__ hpre,
                                                const float* __restrict__ w,
                                                const float* __restrict__ bias,
                                                float* __restrict__ h) {
    int c = blockIdx.y, b = blockIdx.z;
    int p = blockIdx.x * 256 + threadIdx.x;
    int i = p >> 6, j = p & 63;
    const float* wp = w + c * 9;
    const float* src = hpre + ((size_t)b * DI + c) * HW;
    float acc = bias[c];
#pragma unroll
    for (int di = -1; di <= 1; ++di) {
        int ii = i + di;
        if (ii < 0 || ii >= HH) continue;
#pragma unroll
        for (int dj = -1; dj <= 1; ++dj) {
            int jj = j + dj;
            if (jj < 0 || jj >= WW) continue;
            acc = fmaf(wp[(di + 1) * 3 + (dj + 1)], src[ii * WW + jj], acc);
        }
    }
    h[((size_t)b * DI + c) * HW + p] = acc;
}

// ---------------- K3: x_down -> xp column-major [b][w][q][h] ----------------
// grid (128), block 256 = 4 waves. Wave = 96-channel slice; 64 pixels/block.
__global__ __launch_bounds__(256) void k_xdown(const float* __restrict__ h,
                                               const float* __restrict__ w,
                                               float* __restrict__ xpt) {
    __shared__ float red[4][64][17];
    int tid = threadIdx.x;
    int px = tid & 63, cw = tid >> 6;
    int gp = blockIdx.x * 64 + px;
    int b = gp >> 12, p = gp & 4095;
    const float* hb = h + (size_t)b * DI * HW + p;
    int c0 = cw * 96;
    float a[16];
#pragma unroll
    for (int s = 0; s < 16; ++s) a[s] = 0.f;
    for (int cc = 0; cc < 96; cc += 4) {
        float h0 = hb[(size_t)(c0 + cc + 0) * HW];
        float h1 = hb[(size_t)(c0 + cc + 1) * HW];
        float h2 = hb[(size_t)(c0 + cc + 2) * HW];
        float h3 = hb[(size_t)(c0 + cc + 3) * HW];
#pragma unroll
        for (int s = 0; s < 16; ++s) {
            const float* ws = w + (size_t)s * DI + c0 + cc;  // wave-uniform -> s_load
            a[s] = fmaf(ws[0], h0, fmaf(ws[1], h1, fmaf(ws[2], h2, fmaf(ws[3], h3, a[s]))));
        }
    }
#pragma unroll
    for (int s = 0; s < 16; ++s) red[cw][px][s] = a[s];
    __syncthreads();
    int sg = tid >> 6;  // state quad
    float4 r;
    float* o = &r.x;
#pragma unroll
    for (int j = 0; j < 4; ++j) {
        int s = sg * 4 + j;
        o[j] = red[0][px][s] + red[1][px][s] + red[2][px][s] + red[3][px][s];
    }
    int hp = p >> 6, wp_ = p & 63;
    reinterpret_cast<float4*>(xpt)[(size_t)b * (HW * 4) + (wp_ * 4 + sg) * 64 + hp] = r;
}

// Packed 16-dot: 8 v_pk_fma_f32 in two chains + horizontal add.
__device__ __forceinline__ float dot16p(const v2f* __restrict__ W,
                                        const Q4& a0, const Q4& a1,
                                        const Q4& a2, const Q4& a3) {
    v2f t0 = W[0] * a0.v2[0];
    v2f t1 = W[1] * a0.v2[1];
    t0 = __builtin_elementwise_fma(W[2], a1.v2[0], t0);
    t1 = __builtin_elementwise_fma(W[3], a1.v2[1], t1);
    t0 = __builtin_elementwise_fma(W[4], a2.v2[0], t0);
    t1 = __builtin_elementwise_fma(W[5], a2.v2[1], t1);
    t0 = __builtin_elementwise_fma(W[6], a3.v2[0], t0);
    t1 = __builtin_elementwise_fma(W[7], a3.v2[1], t1);
    v2f t = t0 + t1;
    return t.x + t.y;
}

// ---------------- K4: fused gate-recurrent scan, all 4 directions ----------------
// grid (384, 2), block 256 (4 waves = 4 directions, lane = h). r17 build.
__global__ __launch_bounds__(256, 3) void k_scan(const float* __restrict__ h,
                                                 const float* __restrict__ xpt,
                                                 const float* __restrict__ wup,
                                                 const float* __restrict__ lup,
                                                 const float* __restrict__ uup,
                                                 const float* __restrict__ dup,
                                                 const float* __restrict__ mw,
                                                 float* __restrict__ y) {
    int c = blockIdx.x, b = blockIdx.y;
    int tid = threadIdx.x;
    int d = tid >> 6, hl = tid & 63;

    __shared__ float htile[64][65];
    __shared__ float acc[64][65];

    const float* hb = h + ((size_t)b * DI + c) * HW;
    for (int i = tid; i < HW; i += 256) {
        htile[i >> 6][i & 63] = hb[i];
        acc[i >> 6][i & 63] = 0.f;
    }

    int row = d * DI + c;
    const float* p1 = wup + (size_t)row * DS;
    const float* p2 = wup + (size_t)(4 * DI + row) * DS;
    const float* p3 = wup + (size_t)(8 * DI + row) * DS;
    const float* pL = lup + (size_t)row * DS;
    const float* pU = uup + (size_t)row * DS;
    const float* pD = dup + (size_t)row * DS;
    float md = mw[d];
    v2f w1p[8], w2p[8], w3p[8], wLp[8], wUp[8], wDp[8];
#pragma unroll
    for (int k = 0; k < 8; ++k) {
        w1p[k] = *reinterpret_cast<const v2f*>(p1 + 2 * k);
        w2p[k] = *reinterpret_cast<const v2f*>(p2 + 2 * k);
        w3p[k] = *reinterpret_cast<const v2f*>(p3 + 2 * k);
        wLp[k] = *reinterpret_cast<const v2f*>(pL + 2 * k);
        wUp[k] = md * *reinterpret_cast<const v2f*>(pU + 2 * k);
        wDp[k] = md * *reinterpret_cast<const v2f*>(pD + 2 * k);
    }

    int xstep = (d & 1) ? 65 : 1;
    int xbase = (d & 1) ? hl : hl * 65;
    if (d & 2) { xbase += xstep * 63; xstep = -xstep; }
    const float* xptr = &htile[0][0] + xbase;

    bool isTop = (hl == 0), isBot = (hl == 63);
    float topMul = isTop ? 0.f : 1.f;
    float botMul = isBot ? 0.f : 1.f;

    float* accp = &acc[hl][0];

    const float4* xg = reinterpret_cast<const float4*>(xpt) + (size_t)b * (HW * 4) + hl;

#define LOADQ(R0, R1, R2, R3, wcol) { \
    const float4* pp_ = xg + (size_t)(wcol) * 256; \
    R0.f4 = pp_[0]; R1.f4 = pp_[64]; R2.f4 = pp_[128]; R3.f4 = pp_[192]; }

#define PREP(g1S, g2S, g3S, invS, LS, US, DvS, XS, R0, R1, R2, R3) { \
    g1S = dot16p(w1p, R0, R1, R2, R3); \
    g2S = dot16p(w2p, R0, R1, R2, R3); \
    g3S = dot16p(w3p, R0, R1, R2, R3); \
    LS  = dot16p(wLp, R0, R1, R2, R3); \
    US  = dot16p(wUp, R0, R1, R2, R3); \
    DvS = dot16p(wDp, R0, R1, R2, R3); \
    g1S = fsig(g1S); g2S = fsig(g2S); g3S = fsig(g3S); \
    float ss_ = fmaf(g1S, topMul, fmaf(g3S, botMul, g2S)); \
    invS = fastrcp(fmaxf(ss_, 1e-7f)); \
    XS = *xptr; xptr += xstep; }

#define COMB(g1S, g2S, g3S, invS, LS, US, DvS, XS) { \
    float upv_ = topMul * shift_up(hprev); \
    float dnv_ = botMul * shift_dn(hprev); \
    float hnew_ = fmaf(LS, XS, invS * fmaf(g1S, upv_, fmaf(g2S, hprev, g3S * dnv_))); \
    atomicAdd(accp, fmaf(hnew_, US, XS * DvS)); accp += 1; \
    hprev = hnew_; }

    Q4 A0, A1, A2, A3, B0, B1, B2, B3;
    float g1a, g2a, g3a, inva, La, Ua, Dva, Xa;
    float g1b, g2b, g3b, invb, Lb, Ub, Dvb, Xb;
    float hprev = 0.f;

    LOADQ(A0, A1, A2, A3, 0);
    __syncthreads();
    LOADQ(B0, B1, B2, B3, 1);

    for (int w = 0; w < 64; w += 2) {
        PREP(g1a, g2a, g3a, inva, La, Ua, Dva, Xa, A0, A1, A2, A3);
        int wn2 = (w + 2 < 64) ? w + 2 : 63;
        LOADQ(A0, A1, A2, A3, wn2);
        COMB(g1a, g2a, g3a, inva, La, Ua, Dva, Xa);
        PREP(g1b, g2b, g3b, invb, Lb, Ub, Dvb, Xb, B0, B1, B2, B3);
        int wn3 = (w + 3 < 64) ? w + 3 : 63;
        LOADQ(B0, B1, B2, B3, wn3);
        COMB(g1b, g2b, g3b, invb, Lb, Ub, Dvb, Xb);
    }
#undef LOADQ
#undef PREP
#undef COMB

    __syncthreads();
    float* yb = y + ((size_t)b * DI + c) * HW;
    for (int i = tid; i < HW; i += 256) yb[i] = acc[i >> 6][i & 63];
}

// ---------------- K5: LayerNorm2d fused with GRN sumsq ----------------
// grid (512), block 256. gxsum must be zeroed beforehand.
__global__ __launch_bounds__(256) void k_ln(float* __restrict__ y,
                                            const float* __restrict__ nw,
                                            const float* __restrict__ nb,
                                            float* __restrict__ gxsum) {
    int lpx = threadIdx.x & 15, chunk = threadIdx.x >> 4;
    int gp = blockIdx.x * 16 + lpx;  // global pixel 0..8191
    int b = gp >> 12, p = gp & 4095;
    float* yb = y + (size_t)b * DI * HW + p;

    float vv[24];
    float s = 0.f, s2 = 0.f;
#pragma unroll
    for (int ci = 0; ci < 24; ++ci) {
        float v = yb[(size_t)(chunk * 24 + ci) * HW];
        vv[ci] = v;
        s += v;
        s2 = fmaf(v, v, s2);
    }
    __shared__ float S[16][17], S2[16][17];
    __shared__ float ss[16][385];
    S[chunk][lpx] = s;
    S2[chunk][lpx] = s2;
    __syncthreads();
    float ts = 0.f, ts2 = 0.f;
#pragma unroll
    for (int k = 0; k < 16; ++k) { ts += S[k][lpx]; ts2 += S2[k][lpx]; }
    float mu = ts * (1.0f / DI);
    float var = ts2 * (1.0f / DI) - mu * mu;
    float inv = rsqrtf(var + 1e-5f);
#pragma unroll
    for (int ci = 0; ci < 24; ++ci) {
        int cch = chunk * 24 + ci;
        float v = (vv[ci] - mu) * inv;
        float o = fmaf(v, nw[cch], nb[cch]);
        yb[(size_t)cch * HW] = o;
        ss[lpx][cch] = o * o;
    }
    __syncthreads();
    for (int cc = threadIdx.x; cc < DI; cc += 256) {
        float t = 0.f;
#pragma unroll
        for (int k = 0; k < 16; ++k) t += ss[k][cc];
        atomicAdd(&gxsum[b * DI + cc], t);
    }
}

// ---------------- K8: out_proj GEMM with inline GRN scale/shift ----------------
// grid (16, 24, 2), block 256. Prologue recomputes sc[384] into LDS from
// gxsum (replaces the k_grnscale launch); GEMM body identical to r17.
__global__ __launch_bounds__(256, 3) void k_outproj(const float* __restrict__ y,
                                                    const float* __restrict__ w,
                                                    const float* __restrict__ gxsum,
                                                    const float* __restrict__ gamma,
                                                    const float* __restrict__ beta,
                                                    float* __restrict__ out) {
    int og = blockIdx.y, b = blockIdx.z;
    int tid = threadIdx.x;
    __shared__ float scl[DI];
    __shared__ float red[4];
    __shared__ float meanv;
    {
        const float* g = gxsum + b * DI;
        float g0 = sqrtf(g[tid]);
        float g1 = (tid < DI - 256) ? sqrtf(g[tid + 256]) : 0.f;
        float sgx = g0 + g1;
#pragma unroll
        for (int o = 32; o > 0; o >>= 1) sgx += __shfl_down(sgx, o);
        if ((tid & 63) == 0) red[tid >> 6] = sgx;
        __syncthreads();
        if (tid == 0) meanv = (red[0] + red[1] + red[2] + red[3]) * (1.0f / DI);
        __syncthreads();
        float m = meanv + 1e-6f;
        scl[tid] = 1.0f + gamma[tid] * (g0 / m);
        if (tid < DI - 256) scl[tid + 256] = 1.0f + gamma[tid + 256] * (g1 / m);
        __syncthreads();
    }
    int p = blockIdx.x * 256 + tid;
    const float* wr = w + (size_t)og * 8 * DI;
    const float* yb = y + (size_t)b * DI * HW + p;
    float acc[8];
#pragma unroll
    for (int j = 0; j < 8; ++j) acc[j] = 0.f;
    for (int c = 0; c < DI; c += 4) {
        float v0 = fmaf(yb[(size_t)(c + 0) * HW], scl[c + 0], beta[c + 0]);
        float v1 = fmaf(yb[(size_t)(c + 1) * HW], scl[c + 1], beta[c + 1]);
        float v2 = fmaf(yb[(size_t)(c + 2) * HW], scl[c + 2], beta[c + 2]);
        float v3 = fmaf(yb[(size_t)(c + 3) * HW], scl[c + 3], beta[c + 3]);
#pragma unroll
        for (int j = 0; j < 8; ++j) {
            const float* wj = wr + j * DI + c;  // wave-uniform -> SGPR
            acc[j] = fmaf(wj[0], v0, fmaf(wj[1], v1, fmaf(wj[2], v2, fmaf(wj[3], v3, acc[j]))));
        }
    }
    float* ob = out + (size_t)b * DM * HW + (size_t)(og * 8) * HW + p;
#pragma unroll
    for (int j = 0; j < 8; ++j) ob[(size_t)j * HW] = acc[j];
}

extern "C" void kernel_launch(void* const* d_in, const int* in_sizes, int n_in,
                              void* d_out, int out_size, void* d_ws, size_t ws_size,
                              hipStream_t stream) {
    (void)in_sizes; (void)n_in; (void)out_size; (void)ws_size;
    const float* x          = (const float*)d_in[0];
    const float* in_proj_w  = (const float*)d_in[1];
    const float* dwconv_w   = (const float*)d_in[2];
    const float* dwconv_b   = (const float*)d_in[3];
    const float* x_down_w   = (const float*)d_in[4];
    const float* w_up_w     = (const float*)d_in[5];
    const float* l_up_w     = (const float*)d_in[6];
    const float* u_up_w     = (const float*)d_in[7];
    const float* d_up_w     = (const float*)d_in[8];
    const float* m_w        = (const float*)d_in[9];
    const float* grn_gamma  = (const float*)d_in[10];
    const float* grn_beta   = (const float*)d_in[11];
    const float* norm_w     = (const float*)d_in[12];
    const float* norm_b     = (const float*)d_in[13];
    const float* out_proj_w = (const float*)d_in[14];

    float* ws = (float*)d_ws;
    const size_t NBIG = (size_t)Bn * DI * HW;
    float* hpre = ws;                  // [B,DI,H,W], later reused as y
    float* hbuf = ws + NBIG;           // [B,DI,H,W] post-dwconv
    float* xpt  = ws + 2 * NBIG;       // [B,W,4,64] column-major xp
    float* gx   = ws + 2 * NBIG + (size_t)Bn * HW * DS;
    float* y    = hpre;

    k_inproj<<<dim3(16, 24, 2), 256, 0, stream>>>(x, in_proj_w, hpre);
    k_dwconv<<<dim3(16, DI, Bn), 256, 0, stream>>>(hpre, dwconv_w, dwconv_b, hbuf);
    k_xdown<<<dim3(128), 256, 0, stream>>>(hbuf, x_down_w, xpt);
    k_scan<<<dim3(DI, Bn), 256, 0, stream>>>(hbuf, xpt, w_up_w, l_up_w, u_up_w,
                                             d_up_w, m_w, y);
    hipMemsetAsync(gx, 0, Bn * DI * sizeof(float), stream);
    k_ln<<<dim3(512), 256, 0, stream>>>(y, norm_w, norm_b, gx);
    k_outproj<<<dim3(16, 24, 2), 256, 0, stream>>>(y, out_proj_w, gx, grn_gamma,
                                                   grn_beta, (float*)d_out);
}